// Round 14
// baseline (17.199 us; speedup 1.0000x reference)
//
#include <hip/hip_runtime.h>
#include <hip/hip_fp16.h>

#define MQ 32
#define NG 256
#define DD 128

typedef __fp16 fp16x2 __attribute__((ext_vector_type(2)));
union H2U { fp16x2 v; __half2 h; unsigned int u; };

__device__ __forceinline__ __half2 cvt_pkrtz(float a, float b) {
    H2U r; r.v = __builtin_amdgcn_cvt_pkrtz(a, b); return r.h;
}

// packed f16 max -> v_pk_max_f16 (ROCm headers lack __hmax2)
__device__ __forceinline__ __half2 hmax2(__half2 a, __half2 b) {
    H2U x, y, r; x.h = a; y.h = b;
    r.v = __builtin_elementwise_max(x.v, y.v);
    return r.h;
}

// full-wave butterfly reduction (64 lanes)
__device__ __forceinline__ float wred64(float v) {
    #pragma unroll
    for (int o = 32; o > 0; o >>= 1) v += __shfl_xor(v, o);
    return v;
}
// half-wave reduction (32 lanes)
__device__ __forceinline__ float hred32(float v) {
    #pragma unroll
    for (int o = 16; o > 0; o >>= 1) v += __shfl_xor(v, o);
    return v;
}

__global__ __launch_bounds__(256)
void InferenceXtt_kernel(const float* __restrict__ qf,
                         const float* __restrict__ x,
                         const float* __restrict__ Mp,
                         const float* __restrict__ zep,
                         float* __restrict__ out) {
    __shared__ __half2 ua_sh[DD][8];        // 4 KB: splat (u,u) per (row d, pair p)
    __shared__ float dist0_sh[8];
    __shared__ float pen_sh[4][8];

    const int t = threadIdx.x;
    const int w = t >> 6;                  // wave 0..3
    const int l = t & 63;
    const int k = l & 31;
    const int d0 = k * 4;                  // this lane's 4 b-columns
    const int half = l >> 5;
    const int i  = blockIdx.x >> 5;        // query 0..31
    const int j0 = (blockIdx.x & 31) * 8;  // 8 pairs per block

    const float ze = zep[0];
    const __half2 ze2 = cvt_pkrtz(ze, ze); // f16 clamp threshold (splat)

    // ---- prep: half-wave group p = t>>5 owns pair p; float4 loads; RTZ splats ----
    {
        const int p = t >> 5;              // 0..7
        const float4 qv = *(const float4*)&qf[i * DD + d0];
        const float4 xv = *(const float4*)&x[(j0 + p) * DD + d0];
        const float u0 = fmaxf(qv.x, xv.x), u1 = fmaxf(qv.y, xv.y);
        const float u2 = fmaxf(qv.z, xv.z), u3 = fmaxf(qv.w, xv.w);
        const float v0 = fminf(qv.x, xv.x), v1 = fminf(qv.y, xv.y);
        const float v2 = fminf(qv.z, xv.z), v3 = fminf(qv.w, xv.w);
        ua_sh[d0 + 0][p] = cvt_pkrtz(u0, u0);   // splat, RTZ (one-time conflicts OK)
        ua_sh[d0 + 1][p] = cvt_pkrtz(u1, u1);
        ua_sh[d0 + 2][p] = cvt_pkrtz(u2, u2);
        ua_sh[d0 + 3][p] = cvt_pkrtz(u3, u3);
        const float su = hred32((u0 + u1) + (u2 + u3));  // f32 for dist0
        const float sv = hred32((v0 + v1) + (v2 + v3));
        if (k == 0) dist0_sh[p] = sv / su;
    }

    // ---- ub2 register tile from global (same RTZ rounding as ua_sh) ----
    __half2 ub2[8][2];
    {
        const float4 qv = *(const float4*)&qf[i * DD + d0];
        #pragma unroll
        for (int p = 0; p < 8; ++p) {
            const float4 xv = *(const float4*)&x[(j0 + p) * DD + d0];
            ub2[p][0] = cvt_pkrtz(fmaxf(qv.x, xv.x), fmaxf(qv.y, xv.y));
            ub2[p][1] = cvt_pkrtz(fmaxf(qv.z, xv.z), fmaxf(qv.w, xv.w));
        }
    }

    __syncthreads();   // ua_sh ready

    // ---- packed core: acc += max(ze, fma(ua, ub, -m)); 8 pairs per Mp load ----
    __half2 acc2[8][2];
    #pragma unroll
    for (int p = 0; p < 8; ++p) acc2[p][0] = acc2[p][1] = __half2half2(__float2half(0.f));

    const float*   mp_g = &Mp[(w * 32 + half) * DD + d0];
    const __half2* ua_g = &ua_sh[w * 32 + half][0];
    #pragma unroll 4
    for (int s = 0; s < 16; ++s) {
        const float4 mp = *(const float4*)mp_g;        // global dwordx4, L2 hit
        union { uint4 u; __half2 h[4]; } A, B;
        A.u = *(const uint4*)ua_g;                     // ds_read_b128 broadcast
        B.u = *(const uint4*)(ua_g + 4);
        mp_g += 2 * DD;
        ua_g += 2 * 8;
        const __half2 nm01 = cvt_pkrtz(-mp.x, -mp.y);  // -(Mp) packed, neg in cvt
        const __half2 nm23 = cvt_pkrtz(-mp.z, -mp.w);
        #pragma unroll
        for (int p = 0; p < 8; ++p) {
            const __half2 ua2 = (p < 4) ? A.h[p] : B.h[p - 4];
            const __half2 w01 = __hfma2(ua2, ub2[p][0], nm01);
            const __half2 w23 = __hfma2(ua2, ub2[p][1], nm23);
            acc2[p][0] = __hadd2(acc2[p][0], hmax2(ze2, w01));
            acc2[p][1] = __hadd2(acc2[p][1], hmax2(ze2, w23));
        }
    }

    // ---- reductions ----
    #pragma unroll
    for (int p = 0; p < 8; ++p) {
        const float S = (__low2float(acc2[p][0]) + __high2float(acc2[p][0]))
                      + (__low2float(acc2[p][1]) + __high2float(acc2[p][1]));
        const float Sr = wred64(S);
        if (l == p) pen_sh[w][p] = Sr;
    }
    __syncthreads();

    if (t < 8) {
        float pen = 0.f;
        #pragma unroll
        for (int ww = 0; ww < 4; ++ww) pen += pen_sh[ww][t];
        out[i * NG + j0 + t] = dist0_sh[t] - 0.001f * pen;
    }
}

extern "C" void kernel_launch(void* const* d_in, const int* in_sizes, int n_in,
                              void* d_out, int out_size, void* d_ws, size_t ws_size,
                              hipStream_t stream) {
    const float* qf = (const float*)d_in[0];
    const float* x  = (const float*)d_in[1];
    const float* Mp = (const float*)d_in[2];
    const float* ze = (const float*)d_in[3];
    float* out = (float*)d_out;
    InferenceXtt_kernel<<<dim3(MQ * 32), dim3(256), 0, stream>>>(qf, x, Mp, ze, out);
}

// Round 15
// 15.842 us; speedup vs baseline: 1.0856x; 1.0856x over previous
//
#include <hip/hip_runtime.h>
#include <hip/hip_fp16.h>

#define MQ 32
#define NG 256
#define DD 128

typedef __fp16 fp16x2 __attribute__((ext_vector_type(2)));
union H2U { fp16x2 v; __half2 h; unsigned int u; };

__device__ __forceinline__ __half2 cvt_pkrtz(float a, float b) {
    H2U r; r.v = __builtin_amdgcn_cvt_pkrtz(a, b); return r.h;
}

// packed f16 max -> v_pk_max_f16 (ROCm headers lack __hmax2)
__device__ __forceinline__ __half2 hmax2(__half2 a, __half2 b) {
    H2U x, y, r; x.h = a; y.h = b;
    r.v = __builtin_elementwise_max(x.v, y.v);
    return r.h;
}

// full-wave butterfly reduction (64 lanes)
__device__ __forceinline__ float wred64(float v) {
    #pragma unroll
    for (int o = 32; o > 0; o >>= 1) v += __shfl_xor(v, o);
    return v;
}

__global__ __launch_bounds__(256)
void InferenceXtt_kernel(const float* __restrict__ qf,
                         const float* __restrict__ x,
                         const float* __restrict__ Mp,
                         const float* __restrict__ zep,
                         float* __restrict__ out) {
    __shared__ __half2 ua_sh[DD][4];        // 2 KB: splat (u,u) per (row d, pair p)
    __shared__ float dist0_sh[4];
    __shared__ float pen_sh[4][4];

    const int t = threadIdx.x;
    const int w = t >> 6;                  // wave 0..3
    const int l = t & 63;
    const int k = l & 31;
    const int d0 = k * 4;                  // this lane's 4 b-columns
    const int half = l >> 5;
    const int i  = blockIdx.x >> 6;        // query 0..31
    const int j0 = (blockIdx.x & 63) * 4;  // 4 pairs per block

    const float ze = zep[0];
    const __half2 ze2 = cvt_pkrtz(ze, ze); // f16 clamp threshold (splat)

    // ---- prep: wave w owns pair p=w; coalesced scalar loads; RTZ splats to LDS ----
    {
        const float q0 = qf[i * DD + l];
        const float q1 = qf[i * DD + l + 64];
        const float x0 = x[(j0 + w) * DD + l];
        const float x1 = x[(j0 + w) * DD + l + 64];
        const float u0 = fmaxf(q0, x0), u1 = fmaxf(q1, x1);
        const float v0 = fminf(q0, x0), v1 = fminf(q1, x1);
        ua_sh[l][w]      = cvt_pkrtz(u0, u0);   // splat, RTZ
        ua_sh[l + 64][w] = cvt_pkrtz(u1, u1);
        const float su = wred64(u0 + u1);       // f32 for dist0
        const float sv = wred64(v0 + v1);
        if (l == 0) dist0_sh[w] = sv / su;
    }

    // ---- ub2 register tile from global (same RTZ rounding as ua_sh) ----
    __half2 ub2[4][2];
    {
        const float4 qv = *(const float4*)&qf[i * DD + d0];
        #pragma unroll
        for (int p = 0; p < 4; ++p) {
            const float4 xv = *(const float4*)&x[(j0 + p) * DD + d0];
            ub2[p][0] = cvt_pkrtz(fmaxf(qv.x, xv.x), fmaxf(qv.y, xv.y));
            ub2[p][1] = cvt_pkrtz(fmaxf(qv.z, xv.z), fmaxf(qv.w, xv.w));
        }
    }

    __syncthreads();   // ua_sh ready

    // ---- packed core: acc += max(ze, fma(ua, ub, -m)) directly ----
    __half2 acc2[4][2];
    #pragma unroll
    for (int p = 0; p < 4; ++p) acc2[p][0] = acc2[p][1] = __half2half2(__float2half(0.f));

    const float*   mp_g = &Mp[(w * 32 + half) * DD + d0];
    const __half2* ua_g = &ua_sh[w * 32 + half][0];
    #pragma unroll 4
    for (int s = 0; s < 16; ++s) {
        const float4 mp = *(const float4*)mp_g;        // global dwordx4, L2 hit
        union { uint4 u; __half2 h[4]; } A;
        A.u = *(const uint4*)ua_g;                     // ds_read_b128 broadcast
        mp_g += 2 * DD;
        ua_g += 2 * 4;
        const __half2 nm01 = cvt_pkrtz(-mp.x, -mp.y);  // -(Mp) packed, neg in cvt
        const __half2 nm23 = cvt_pkrtz(-mp.z, -mp.w);
        #pragma unroll
        for (int p = 0; p < 4; ++p) {
            const __half2 w01 = __hfma2(A.h[p], ub2[p][0], nm01);
            const __half2 w23 = __hfma2(A.h[p], ub2[p][1], nm23);
            acc2[p][0] = __hadd2(acc2[p][0], hmax2(ze2, w01));
            acc2[p][1] = __hadd2(acc2[p][1], hmax2(ze2, w23));
        }
    }

    // ---- reductions ----
    #pragma unroll
    for (int p = 0; p < 4; ++p) {
        const float S = (__low2float(acc2[p][0]) + __high2float(acc2[p][0]))
                      + (__low2float(acc2[p][1]) + __high2float(acc2[p][1]));
        const float Sr = wred64(S);
        if (l == p) pen_sh[w][p] = Sr;
    }
    __syncthreads();

    if (t < 4) {
        float pen = 0.f;
        #pragma unroll
        for (int ww = 0; ww < 4; ++ww) pen += pen_sh[ww][t];
        out[i * NG + j0 + t] = dist0_sh[t] - 0.001f * pen;
    }
}

extern "C" void kernel_launch(void* const* d_in, const int* in_sizes, int n_in,
                              void* d_out, int out_size, void* d_ws, size_t ws_size,
                              hipStream_t stream) {
    const float* qf = (const float*)d_in[0];
    const float* x  = (const float*)d_in[1];
    const float* Mp = (const float*)d_in[2];
    const float* ze = (const float*)d_in[3];
    float* out = (float*)d_out;
    InferenceXtt_kernel<<<dim3(MQ * 64), dim3(256), 0, stream>>>(qf, x, Mp, ze, out);
}